// Round 21
// baseline (260.507 us; speedup 1.0000x reference)
//
#include <hip/hip_runtime.h>
#include <stdint.h>
#include <math.h>

#define NB   2
#define NQ   100
#define NCLS 133
#define NCL1 134
#define HM   160
#define WM   160
#define HO   640
#define WO   640
#define G    4          // query-split groups for argmax
#define NCELL (HM*WM)
#define SEMROWS 32      // output rows per sem block

typedef float f32x4 __attribute__((ext_vector_type(4)));

static __device__ __forceinline__ int clampi(int v, int lo, int hi){ return v<lo?lo:(v>hi?hi:v); }
static __device__ __forceinline__ double dsig(float x){ return 1.0/(1.0+exp(-(double)x)); }

// ---------------- kernel 1: per-query softmax stats (f64) + compaction + zero areas ----------------
__global__ void k_classify(const float* __restrict__ logits, double* __restrict__ scores,
                           int* __restrict__ labels, int* __restrict__ keepf,
                           int* __restrict__ kq, int* __restrict__ Kc,
                           int* __restrict__ marea, int* __restrict__ oarea)
{
  int t = threadIdx.x;
  for (int i=t;i<NB*NQ;i+=blockDim.x){ marea[i]=0; oarea[i]=0; }
  if (t < NB*NQ){
    const float* l = logits + (size_t)t*NCL1;
    float mx = l[0]; int am = 0;
    for (int c=1;c<NCL1;++c){ float v=l[c]; if (v>mx){ mx=v; am=c; } }
    double s = 0.0;
    for (int c=0;c<NCL1;++c) s += exp((double)l[c] - (double)mx);
    double sc = 1.0/s;
    scores[t] = sc; labels[t] = am;
    keepf[t] = (am < NCLS && sc > 0.4) ? 1 : 0;
  }
  __syncthreads();
  if (t < NB){
    int k = 0;
    for (int q=0;q<NQ;++q) if (keepf[t*NQ+q]) kq[t*NQ + (k++)] = q;
    Kc[t] = k;
  }
}

// ---------------- kernel 2: sigmoid of KEPT masks only -> f64 (argmax) + f32 (sem) ----------------
__global__ void k_sigmoid(const float* __restrict__ masks, double* __restrict__ sig64,
                          float* __restrict__ sig32, const int* __restrict__ keepf)
{
  int gid = blockIdx.x*blockDim.x + threadIdx.x;      // float4 index
  int bq  = gid / (HM*WM/4);
  if (!keepf[bq]) return;                             // non-kept planes never read downstream
  float4 v = reinterpret_cast<const float4*>(masks)[gid];
  double o0 = dsig(v.x), o1 = dsig(v.y), o2 = dsig(v.z), o3 = dsig(v.w);
  double2 d0; d0.x=o0; d0.y=o1;
  double2 d1; d1.x=o2; d1.y=o3;
  reinterpret_cast<double2*>(sig64)[gid*2]   = d0;
  reinterpret_cast<double2*>(sig64)[gid*2+1] = d1;
  float4 f; f.x=(float)o0; f.y=(float)o1; f.z=(float)o2; f.w=(float)o3;
  reinterpret_cast<float4*>(sig32)[gid] = f;
}

// ---------------- kernel 3a: split-K argmax partials — barrier-synced block staging ----------------
// Block = 16x16 cells (256 thr). Shared 18x18 halo patch; stage -> barrier -> compute -> barrier.
// Output packed u64 = (f64 best & ~127) | (127-q): positives compare as unsigned; sub-2^-45
// ties resolve to smallest q = jnp.argmax first-wins.
__global__ __launch_bounds__(256) void k_argmax_part(const double* __restrict__ sig64,
        const double* __restrict__ scores, const int* __restrict__ kq,
        const int* __restrict__ Kc, unsigned long long* __restrict__ ppack,
        int* __restrict__ oarea)
{
  __shared__ double patch[18][18];
  __shared__ int oacc[32];               // Kg <= ceil(100/G)=25 with G=4
  const int b    = blockIdx.z / G;
  const int g    = blockIdx.z % G;
  const int tid  = threadIdx.x;
  const int tx   = tid & 15, ty = tid >> 4;
  const int cj   = blockIdx.x*16 + tx;
  const int ci   = blockIdx.y*16 + ty;
  const int gr0  = blockIdx.y*16 - 1;
  const int gc0  = blockIdx.x*16 - 1;
  const int K   = Kc[b];
  const int Kg  = (K + G - 1) / G;
  const int k0  = g*Kg;
  const int k1  = min(K, k0 + Kg);

  if (tid < 32) oacc[tid] = 0;

  double best[4][4];
  int    bq[4][4];
  #pragma unroll
  for (int r=0;r<4;++r)
    #pragma unroll
    for (int s=0;s<4;++s){ best[r][s] = -1.0; bq[r][s] = 0; }

  const int i0 = tid,     p0r = i0/18, p0c = i0-18*p0r;
  const int i1 = tid+256; int p1r = i1/18, p1c = i1-18*p1r;
  const int a0 = clampi(gr0+p0r,0,HM-1)*WM + clampi(gc0+p0c,0,WM-1);
  const int a1 = clampi(gr0+p1r,0,HM-1)*WM + clampi(gc0+p1c,0,WM-1);

  __syncthreads();   // oacc zero visible

  for (int k=k0;k<k1;++k){
    const int    q  = kq[b*NQ+k];
    const double sc = scores[b*NQ+q];
    const double* sp = sig64 + (size_t)(b*NQ + q)*HM*WM;

    patch[p0r][p0c] = sp[a0];
    if (i1 < 324) patch[p1r][p1c] = sp[a1];
    __syncthreads();

    double v[3][3];
    #pragma unroll
    for (int rr=0;rr<3;++rr)
      #pragma unroll
      for (int cc=0;cc<3;++cc)
        v[rr][cc] = patch[ty+rr][tx+cc];

    int cnt = 0;
    #pragma unroll
    for (int r=0;r<4;++r){
      const double wa = (r==0)?0.375:(r==1)?0.125:(r==2)?0.875:0.625;
      const double wb = (r==0)?0.625:(r==1)?0.875:(r==2)?0.125:0.375;
      const int ra = (r<2)?0:1, rb = ra+1;
      const bool vedge = (r<2) ? (ci==0) : (ci==HM-1);
      const int  vsel  = (r<2) ? rb : ra;
      double t0 = vedge ? v[vsel][0] : (wa*v[ra][0] + wb*v[rb][0]);
      double t1 = vedge ? v[vsel][1] : (wa*v[ra][1] + wb*v[rb][1]);
      double t2 = vedge ? v[vsel][2] : (wa*v[ra][2] + wb*v[rb][2]);
      double u[4];
      u[0] = (cj==0)    ? t1 : (0.375*t0 + 0.625*t1);
      u[1] = (cj==0)    ? t1 : (0.125*t0 + 0.875*t1);
      u[2] = (cj==WM-1) ? t1 : (0.875*t1 + 0.125*t2);
      u[3] = (cj==WM-1) ? t1 : (0.625*t1 + 0.375*t2);
      #pragma unroll
      for (int s=0;s<4;++s){
        cnt += (u[s] >= 0.5) ? 1 : 0;
        double val = sc*u[s];
        if (val > best[r][s]){ best[r][s] = val; bq[r][s] = q; }
      }
    }
    #pragma unroll
    for (int o2=32;o2>0;o2>>=1) cnt += __shfl_down(cnt, o2);
    if ((tid & 63) == 0) atomicAdd(&oacc[k-k0], cnt);

    __syncthreads();
  }

  if (tid < k1-k0){
    int cv = oacc[tid];
    if (cv) atomicAdd(&oarea[b*NQ + kq[b*NQ+k0+tid]], cv);
  }

  const int cell = ci*WM + cj;
  #pragma unroll
  for (int r=0;r<4;++r)
    #pragma unroll
    for (int s=0;s<4;++s){
      unsigned long long pk = 0ULL;
      if (k0 < k1)
        pk = ((unsigned long long)__double_as_longlong(best[r][s]) & ~127ULL)
           | (unsigned long long)(127 - bq[r][s]);
      size_t idx = ((size_t)((b*G + g)*16 + r*4 + s))*NCELL + cell;
      ppack[idx] = pk;
    }
}

static __device__ __forceinline__ int decode_q(unsigned long long v){
  int q = 127 - (int)(v & 127ULL);
  return clampi(q, 0, NQ-1);
}

// ---------------- kernel 3b: combine packed partials -> winners, mask areas ----------------
__global__ __launch_bounds__(256) void k_argmax_comb(const unsigned long long* __restrict__ ppack,
        uint32_t* __restrict__ mids, int* __restrict__ marea)
{
  __shared__ int hist[NQ];
  const int b   = blockIdx.z;
  const int tid = threadIdx.x;
  const int tx  = tid & 15, ty = tid >> 4;
  const int cj  = blockIdx.x*16 + tx;
  const int ci  = blockIdx.y*16 + ty;
  const int cell= ci*WM + cj;

  for (int i=tid;i<NQ;i+=256) hist[i]=0;
  __syncthreads();

  int bqa[16];
  #pragma unroll
  for (int rs=0;rs<16;++rs){
    unsigned long long cur = 0ULL;
    #pragma unroll
    for (int g2=0;g2<G;++g2){
      unsigned long long v = ppack[((size_t)((b*G + g2)*16 + rs))*NCELL + cell];
      if (v > cur) cur = v;    // u64 max == f64 max (positives); tie -> smaller q
    }
    bqa[rs] = decode_q(cur);
  }

  #pragma unroll
  for (int r=0;r<4;++r){
    uint32_t w = (uint32_t)bqa[r*4+0] | ((uint32_t)bqa[r*4+1]<<8)
               | ((uint32_t)bqa[r*4+2]<<16) | ((uint32_t)bqa[r*4+3]<<24);
    int y = 4*ci + r;
    mids[(b*HO + y)*(WO/4) + cj] = w;
  }
  #pragma unroll
  for (int rs=0;rs<16;++rs)
    atomicAdd(&hist[bqa[rs]], 1);
  __syncthreads();
  for (int i=tid;i<NQ;i+=256)
    if (hist[i]) atomicAdd(&marea[b*NQ+i], hist[i]);
}

// ---------------- kernel 4: accept test + cumsum ids + per-class lists ----------------
__global__ void k_finalize(const int* __restrict__ keepf, const int* __restrict__ labels,
                           const int* __restrict__ marea, const int* __restrict__ oarea,
                           float* __restrict__ fid, int* __restrict__ chanoff,
                           int* __restrict__ sortedq)
{
  const int b = blockIdx.x;
  const int tid = threadIdx.x;
  __shared__ int acc[NQ], lab[NQ], cntS[NCLS], start[NCLS];
  if (tid < NQ){
    int i = b*NQ + tid;
    int ma = marea[i], oa = oarea[i];
    acc[tid] = (keepf[i] && ma>0 && oa>0 && ((double)ma > 0.8*(double)oa)) ? 1 : 0;
    lab[tid] = labels[i];
  }
  if (tid < NCLS) cntS[tid]=0;
  __syncthreads();
  if (tid == 0){
    int A = 0;
    for (int q=0;q<NQ;++q){
      if (acc[q]){ A++; fid[b*NQ+q] = (float)A; cntS[lab[q]]++; }
      else fid[b*NQ+q] = 0.0f;
    }
    int off = 0;
    for (int c=0;c<NCLS;++c){ start[c]=off; chanoff[b*NCL1+c]=off; off += cntS[c]; }
    chanoff[b*NCL1+NCLS] = off;
    for (int q=0;q<NQ;++q)
      if (acc[q]){ int c=lab[q]; sortedq[b*NQ + start[c]] = q; start[c]++; }
  }
}

// ---------------- kernel E: sem_seg occupied channels only (zeros via memset) + fused pan ----------
// Grid (HO/SEMROWS=20, NB*NCLS+2=268). y < 266: sem band (early-return if channel empty —
// the hipMemsetAsync at stream head already wrote zeros at fill-engine BW). y >= 266: pan.
__global__ __launch_bounds__(256) void k_sem_pan(const float* __restrict__ sig32,
        const int* __restrict__ chanoff, const int* __restrict__ sortedq,
        const uint32_t* __restrict__ mids, const float* __restrict__ fid,
        float* __restrict__ out)
{
  const int tid = threadIdx.x;
  if (blockIdx.y >= NB*NCLS){
    const int blk = (blockIdx.y - NB*NCLS)*gridDim.x + blockIdx.x;   // 0..39
    f32x4* ob = reinterpret_cast<f32x4*>(out) + (size_t)NB*NCLS*(HO*(size_t)WO/4);
    #pragma unroll
    for (int j=0;j<20;++j){
      int t = (blk*20 + j)*256 + tid;                 // float4 index, 0..204799
      int b = t / (HO*WO/4);
      uint32_t w = mids[t];
      f32x4 o;
      o.x = fid[b*NQ + (w & 255u)];
      o.y = fid[b*NQ + ((w>>8) & 255u)];
      o.z = fid[b*NQ + ((w>>16) & 255u)];
      o.w = fid[b*NQ + (w>>24)];
      __builtin_nontemporal_store(o, ob + t);
    }
    return;
  }

  const int bc = blockIdx.y;             // b*NCLS + c
  const int b  = bc / NCLS, c = bc - b*NCLS;
  const int s0 = chanoff[b*NCL1+c], s1 = chanoff[b*NCL1+c+1];
  if (s1 == s0) return;                  // zeros already present from hipMemsetAsync

  const int y0 = blockIdx.x * SEMROWS;
  const int ci0 = y0 >> 2;

  __shared__ float row[10][WM];          // input rows ci0-1 .. ci0+8 (clamped)

  f32x4 acc[20];
  #pragma unroll
  for (int ch=0;ch<20;++ch) acc[ch] = (f32x4)(0.f);

  for (int i=s0;i<s1;++i){
    const int q = sortedq[b*NQ+i];
    const float* sp = sig32 + (size_t)(b*NQ+q)*HM*WM;
    for (int i2=tid;i2<10*WM;i2+=256){
      int jr = i2/WM, jc = i2 - jr*WM;
      int gi = clampi(ci0 + jr - 1, 0, HM-1);
      row[jr][jc] = sp[gi*WM + jc];
    }
    __syncthreads();
    #pragma unroll
    for (int ch=0;ch<20;++ch){
      const int idx = ch*256 + tid;      // 0..5119
      const int yo  = idx / WM;          // 0..31
      const int x4  = idx - yo*WM;
      const int y   = y0 + yo;
      const int ci  = y >> 2, r = y & 3;
      const int ciL = ci - ci0 + 1;      // 1..8
      const int ra  = (r<2) ? ciL-1 : ciL;
      const int rb  = ra + 1;
      const bool vedge = (r<2) ? (ci==0) : (ci==HM-1);
      const int cm = max(x4-1,0), cp = min(x4+1,WM-1);
      const float wa = (r==0)?0.375f:(r==1)?0.125f:(r==2)?0.875f:0.625f;
      const float wb = (r==0)?0.625f:(r==1)?0.875f:(r==2)?0.125f:0.375f;
      float am=row[ra][cm], a0=row[ra][x4], ap=row[ra][cp];
      float bm=row[rb][cm], b0=row[rb][x4], bp=row[rb][cp];
      float t0 = vedge ? ((r<2) ? bm : am) : (wa*am + wb*bm);
      float t1 = vedge ? ((r<2) ? b0 : a0) : (wa*a0 + wb*b0);
      float t2 = vedge ? ((r<2) ? bp : ap) : (wa*ap + wb*bp);
      float u0 = (x4==0)    ? t1 : (0.375f*t0 + 0.625f*t1);
      float u1 = (x4==0)    ? t1 : (0.125f*t0 + 0.875f*t1);
      float u2 = (x4==WM-1) ? t1 : (0.875f*t1 + 0.125f*t2);
      float u3 = (x4==WM-1) ? t1 : (0.625f*t1 + 0.375f*t2);
      acc[ch].x = fmaxf(acc[ch].x, u0);
      acc[ch].y = fmaxf(acc[ch].y, u1);
      acc[ch].z = fmaxf(acc[ch].z, u2);
      acc[ch].w = fmaxf(acc[ch].w, u3);
    }
    __syncthreads();
  }

  f32x4* ob = reinterpret_cast<f32x4*>(out) + ((size_t)bc*HO + y0)*(WO/4);
  #pragma unroll
  for (int ch=0;ch<20;++ch)
    __builtin_nontemporal_store(acc[ch], ob + ch*256 + tid);
}

extern "C" void kernel_launch(void* const* d_in, const int* in_sizes, int n_in,
                              void* d_out, int out_size, void* d_ws, size_t ws_size,
                              hipStream_t stream)
{
  const float* logits = (const float*)d_in[0];
  const float* masks  = (const float*)d_in[1];
  float* out = (float*)d_out;

  char* ws = (char*)d_ws;
  size_t off = 0;
  auto alloc = [&](size_t bytes)->void*{
    void* p = ws + off; off = (off + bytes + 255) & ~(size_t)255; return p;
  };
  double*   sig64   = (double*)  alloc((size_t)NB*NQ*HM*WM*sizeof(double));    // 41 MB
  float*    sig32   = (float*)   alloc((size_t)NB*NQ*HM*WM*sizeof(float));     // 20.5 MB
  unsigned long long* ppack = (unsigned long long*)
                               alloc((size_t)NB*G*16*NCELL*sizeof(unsigned long long)); // 26.2 MB
  uint32_t* mids    = (uint32_t*)alloc((size_t)NB*HO*(WO/4)*sizeof(uint32_t));
  double*   scores  = (double*)  alloc(NB*NQ*sizeof(double));
  int*      labels  = (int*)     alloc(NB*NQ*sizeof(int));
  int*      keepf   = (int*)     alloc(NB*NQ*sizeof(int));
  int*      kq      = (int*)     alloc(NB*NQ*sizeof(int));
  int*      Kc      = (int*)     alloc(NB*sizeof(int));
  int*      marea   = (int*)     alloc(NB*NQ*sizeof(int));
  int*      oarea   = (int*)     alloc(NB*NQ*sizeof(int));
  float*    fid     = (float*)   alloc(NB*NQ*sizeof(float));
  int*      chanoff = (int*)     alloc(NB*NCL1*sizeof(int));
  int*      sortedq = (int*)     alloc(NB*NQ*sizeof(int));

  // Zero the entire output via the runtime fill engine (measured 6.9 TB/s vs our
  // kernels' ~4.4 TB/s streaming-store rate). Async on the capture stream — legal
  // under the harness rules (only sync memcpy/malloc/free/events are banned).
  hipMemsetAsync(d_out, 0, (size_t)out_size*sizeof(float), stream);

  hipLaunchKernelGGL(k_classify, dim3(1), dim3(256), 0, stream,
                     logits, scores, labels, keepf, kq, Kc, marea, oarea);
  hipLaunchKernelGGL(k_sigmoid, dim3((NB*NQ*HM*WM/4)/256), dim3(256), 0, stream,
                     masks, sig64, sig32, keepf);
  hipLaunchKernelGGL(k_argmax_part, dim3(WM/16, HM/16, NB*G), dim3(256), 0, stream,
                     sig64, scores, kq, Kc, ppack, oarea);
  hipLaunchKernelGGL(k_argmax_comb, dim3(WM/16, HM/16, NB), dim3(256), 0, stream,
                     ppack, mids, marea);
  hipLaunchKernelGGL(k_finalize, dim3(NB), dim3(192), 0, stream,
                     keepf, labels, marea, oarea, fid, chanoff, sortedq);
  hipLaunchKernelGGL(k_sem_pan, dim3(HO/SEMROWS, NB*NCLS+2), dim3(256), 0, stream,
                     sig32, chanoff, sortedq, mids, fid, out);
}

// Round 22
// 217.165 us; speedup vs baseline: 1.1996x; 1.1996x over previous
//
#include <hip/hip_runtime.h>
#include <stdint.h>
#include <math.h>

#define NB   2
#define NQ   100
#define NCLS 133
#define NCL1 134
#define HM   160
#define WM   160
#define HO   640
#define WO   640
#define G    8          // query-split groups for argmax
#define NCELL (HM*WM)
#define SEMROWS 32      // output rows per sem block
#define SIGBLKS ((NB*NQ*HM*WM/4)/256)   // 20000 sigmoid blocks

typedef float f32x4 __attribute__((ext_vector_type(4)));

static __device__ __forceinline__ int clampi(int v, int lo, int hi){ return v<lo?lo:(v>hi?hi:v); }
static __device__ __forceinline__ double dsig(float x){ return 1.0/(1.0+exp(-(double)x)); }

// ---------------- kernel A: fused sigmoid (all planes) + classify (last block) ----------------
__global__ void k_sig_cls(const float* __restrict__ masks, double* __restrict__ sig64,
                          float* __restrict__ sig32, const float* __restrict__ logits,
                          double* __restrict__ scores, int* __restrict__ labels,
                          int* __restrict__ keepf, int* __restrict__ kq, int* __restrict__ Kc,
                          int* __restrict__ marea, int* __restrict__ oarea)
{
  if (blockIdx.x < SIGBLKS){
    int gid = blockIdx.x*blockDim.x + threadIdx.x;      // float4 index, all NB*NQ planes
    float4 v = reinterpret_cast<const float4*>(masks)[gid];
    double o0 = dsig(v.x), o1 = dsig(v.y), o2 = dsig(v.z), o3 = dsig(v.w);
    double2 d0; d0.x=o0; d0.y=o1;
    double2 d1; d1.x=o2; d1.y=o3;
    reinterpret_cast<double2*>(sig64)[gid*2]   = d0;
    reinterpret_cast<double2*>(sig64)[gid*2+1] = d1;
    float4 f; f.x=(float)o0; f.y=(float)o1; f.z=(float)o2; f.w=(float)o3;
    reinterpret_cast<float4*>(sig32)[gid] = f;
    return;
  }
  // classify block (independent of sigmoid blocks)
  int t = threadIdx.x;
  for (int i=t;i<NB*NQ;i+=blockDim.x){ marea[i]=0; oarea[i]=0; }
  if (t < NB*NQ){
    const float* l = logits + (size_t)t*NCL1;
    float mx = l[0]; int am = 0;
    for (int c=1;c<NCL1;++c){ float v=l[c]; if (v>mx){ mx=v; am=c; } }
    double s = 0.0;
    for (int c=0;c<NCL1;++c) s += exp((double)l[c] - (double)mx);
    double sc = 1.0/s;
    scores[t] = sc; labels[t] = am;
    keepf[t] = (am < NCLS && sc > 0.4) ? 1 : 0;
  }
  __syncthreads();
  if (t < NB){
    int k = 0;
    for (int q=0;q<NQ;++q) if (keepf[t*NQ+q]) kq[t*NQ + (k++)] = q;
    Kc[t] = k;
  }
}

// ---------------- kernel 3a: split-K argmax partials — barrier-synced block staging ----------------
// Block = 16x16 cells (256 thr). Shared 18x18 halo patch; stage -> barrier -> compute -> barrier.
// Output packed u64 = (f64 best & ~127) | (127-q): positives compare as unsigned; sub-2^-45
// ties resolve to smallest q = jnp.argmax first-wins.
__global__ __launch_bounds__(256) void k_argmax_part(const double* __restrict__ sig64,
        const double* __restrict__ scores, const int* __restrict__ kq,
        const int* __restrict__ Kc, unsigned long long* __restrict__ ppack,
        int* __restrict__ oarea)
{
  __shared__ double patch[18][18];
  __shared__ int oacc[16];
  const int b    = blockIdx.z / G;
  const int g    = blockIdx.z % G;
  const int tid  = threadIdx.x;
  const int tx   = tid & 15, ty = tid >> 4;
  const int cj   = blockIdx.x*16 + tx;
  const int ci   = blockIdx.y*16 + ty;
  const int gr0  = blockIdx.y*16 - 1;
  const int gc0  = blockIdx.x*16 - 1;
  const int K   = Kc[b];
  const int Kg  = (K + G - 1) / G;
  const int k0  = g*Kg;
  const int k1  = min(K, k0 + Kg);

  if (tid < 16) oacc[tid] = 0;

  double best[4][4];
  int    bq[4][4];
  #pragma unroll
  for (int r=0;r<4;++r)
    #pragma unroll
    for (int s=0;s<4;++s){ best[r][s] = -1.0; bq[r][s] = 0; }

  const int i0 = tid,     p0r = i0/18, p0c = i0-18*p0r;
  const int i1 = tid+256; int p1r = i1/18, p1c = i1-18*p1r;
  const int a0 = clampi(gr0+p0r,0,HM-1)*WM + clampi(gc0+p0c,0,WM-1);
  const int a1 = clampi(gr0+p1r,0,HM-1)*WM + clampi(gc0+p1c,0,WM-1);

  __syncthreads();   // oacc zero visible

  for (int k=k0;k<k1;++k){
    const int    q  = kq[b*NQ+k];
    const double sc = scores[b*NQ+q];
    const double* sp = sig64 + (size_t)(b*NQ + q)*HM*WM;

    patch[p0r][p0c] = sp[a0];
    if (i1 < 324) patch[p1r][p1c] = sp[a1];
    __syncthreads();

    double v[3][3];
    #pragma unroll
    for (int rr=0;rr<3;++rr)
      #pragma unroll
      for (int cc=0;cc<3;++cc)
        v[rr][cc] = patch[ty+rr][tx+cc];

    int cnt = 0;
    #pragma unroll
    for (int r=0;r<4;++r){
      const double wa = (r==0)?0.375:(r==1)?0.125:(r==2)?0.875:0.625;
      const double wb = (r==0)?0.625:(r==1)?0.875:(r==2)?0.125:0.375;
      const int ra = (r<2)?0:1, rb = ra+1;
      const bool vedge = (r<2) ? (ci==0) : (ci==HM-1);
      const int  vsel  = (r<2) ? rb : ra;
      double t0 = vedge ? v[vsel][0] : (wa*v[ra][0] + wb*v[rb][0]);
      double t1 = vedge ? v[vsel][1] : (wa*v[ra][1] + wb*v[rb][1]);
      double t2 = vedge ? v[vsel][2] : (wa*v[ra][2] + wb*v[rb][2]);
      double u[4];
      u[0] = (cj==0)    ? t1 : (0.375*t0 + 0.625*t1);
      u[1] = (cj==0)    ? t1 : (0.125*t0 + 0.875*t1);
      u[2] = (cj==WM-1) ? t1 : (0.875*t1 + 0.125*t2);
      u[3] = (cj==WM-1) ? t1 : (0.625*t1 + 0.375*t2);
      #pragma unroll
      for (int s=0;s<4;++s){
        cnt += (u[s] >= 0.5) ? 1 : 0;
        double val = sc*u[s];
        if (val > best[r][s]){ best[r][s] = val; bq[r][s] = q; }
      }
    }
    #pragma unroll
    for (int o2=32;o2>0;o2>>=1) cnt += __shfl_down(cnt, o2);
    if ((tid & 63) == 0) atomicAdd(&oacc[k-k0], cnt);

    __syncthreads();
  }

  if (tid < k1-k0){
    int cv = oacc[tid];
    if (cv) atomicAdd(&oarea[b*NQ + kq[b*NQ+k0+tid]], cv);
  }

  const int cell = ci*WM + cj;
  #pragma unroll
  for (int r=0;r<4;++r)
    #pragma unroll
    for (int s=0;s<4;++s){
      unsigned long long pk = 0ULL;
      if (k0 < k1)
        pk = ((unsigned long long)__double_as_longlong(best[r][s]) & ~127ULL)
           | (unsigned long long)(127 - bq[r][s]);
      size_t idx = ((size_t)((b*G + g)*16 + r*4 + s))*NCELL + cell;
      ppack[idx] = pk;
    }
}

static __device__ __forceinline__ int decode_q(unsigned long long v){
  int q = 127 - (int)(v & 127ULL);
  return clampi(q, 0, NQ-1);
}

// ---------------- kernel 3b: combine packed partials -> winners, mask areas ----------------
__global__ __launch_bounds__(256) void k_argmax_comb(const unsigned long long* __restrict__ ppack,
        uint32_t* __restrict__ mids, int* __restrict__ marea)
{
  __shared__ int hist[NQ];
  const int b   = blockIdx.z;
  const int tid = threadIdx.x;
  const int tx  = tid & 15, ty = tid >> 4;
  const int cj  = blockIdx.x*16 + tx;
  const int ci  = blockIdx.y*16 + ty;
  const int cell= ci*WM + cj;

  for (int i=tid;i<NQ;i+=256) hist[i]=0;
  __syncthreads();

  int bqa[16];
  #pragma unroll
  for (int rs=0;rs<16;++rs){
    unsigned long long cur = 0ULL;
    #pragma unroll
    for (int g2=0;g2<G;++g2){
      unsigned long long v = ppack[((size_t)((b*G + g2)*16 + rs))*NCELL + cell];
      if (v > cur) cur = v;    // u64 max == f64 max (positives); tie -> smaller q
    }
    bqa[rs] = decode_q(cur);
  }

  #pragma unroll
  for (int r=0;r<4;++r){
    uint32_t w = (uint32_t)bqa[r*4+0] | ((uint32_t)bqa[r*4+1]<<8)
               | ((uint32_t)bqa[r*4+2]<<16) | ((uint32_t)bqa[r*4+3]<<24);
    int y = 4*ci + r;
    mids[(b*HO + y)*(WO/4) + cj] = w;
  }
  #pragma unroll
  for (int rs=0;rs<16;++rs)
    atomicAdd(&hist[bqa[rs]], 1);
  __syncthreads();
  for (int i=tid;i<NQ;i+=256)
    if (hist[i]) atomicAdd(&marea[b*NQ+i], hist[i]);
}

// ---------------- kernel 4: accept test + cumsum ids + per-class lists ----------------
__global__ void k_finalize(const int* __restrict__ keepf, const int* __restrict__ labels,
                           const int* __restrict__ marea, const int* __restrict__ oarea,
                           float* __restrict__ fid, int* __restrict__ chanoff,
                           int* __restrict__ sortedq)
{
  const int b = blockIdx.x;
  const int tid = threadIdx.x;
  __shared__ int acc[NQ], lab[NQ], cntS[NCLS], start[NCLS];
  if (tid < NQ){
    int i = b*NQ + tid;
    int ma = marea[i], oa = oarea[i];
    acc[tid] = (keepf[i] && ma>0 && oa>0 && ((double)ma > 0.8*(double)oa)) ? 1 : 0;
    lab[tid] = labels[i];
  }
  if (tid < NCLS) cntS[tid]=0;
  __syncthreads();
  if (tid == 0){
    int A = 0;
    for (int q=0;q<NQ;++q){
      if (acc[q]){ A++; fid[b*NQ+q] = (float)A; cntS[lab[q]]++; }
      else fid[b*NQ+q] = 0.0f;
    }
    int off = 0;
    for (int c=0;c<NCLS;++c){ start[c]=off; chanoff[b*NCL1+c]=off; off += cntS[c]; }
    chanoff[b*NCL1+NCLS] = off;
    for (int q=0;q<NQ;++q)
      if (acc[q]){ int c=lab[q]; sortedq[b*NQ + start[c]] = q; start[c]++; }
  }
}

// ---------------- kernel E: sem_seg (32-row bands, contiguous 80KB stores) + fused pan ----------------
// Grid (HO/SEMROWS=20, NB*NCLS+2=268). y < 266: sem band. y >= 266: panoptic ids
// (2 rows x 20 blocks = 40 blocks covering 204800 float4).
__global__ __launch_bounds__(256) void k_sem_pan(const float* __restrict__ sig32,
        const int* __restrict__ chanoff, const int* __restrict__ sortedq,
        const uint32_t* __restrict__ mids, const float* __restrict__ fid,
        float* __restrict__ out)
{
  const int tid = threadIdx.x;
  if (blockIdx.y >= NB*NCLS){
    // ---- pan path: 40 blocks, each 5120 float4 (20 per thread) ----
    const int blk = (blockIdx.y - NB*NCLS)*gridDim.x + blockIdx.x;   // 0..39
    f32x4* ob = reinterpret_cast<f32x4*>(out) + (size_t)NB*NCLS*(HO*(size_t)WO/4);
    #pragma unroll
    for (int j=0;j<20;++j){
      int t = (blk*20 + j)*256 + tid;                 // float4 index, 0..204799
      int b = t / (HO*WO/4);
      uint32_t w = mids[t];
      f32x4 o;
      o.x = fid[b*NQ + (w & 255u)];
      o.y = fid[b*NQ + ((w>>8) & 255u)];
      o.z = fid[b*NQ + ((w>>16) & 255u)];
      o.w = fid[b*NQ + (w>>24)];
      __builtin_nontemporal_store(o, ob + t);
    }
    return;
  }

  const int bc = blockIdx.y;             // b*NCLS + c
  const int b  = bc / NCLS, c = bc - b*NCLS;
  const int y0 = blockIdx.x * SEMROWS;
  const int ci0 = y0 >> 2;
  const int s0 = chanoff[b*NCL1+c], s1 = chanoff[b*NCL1+c+1];

  __shared__ float row[10][WM];          // input rows ci0-1 .. ci0+8 (clamped)

  f32x4 acc[20];
  #pragma unroll
  for (int ch=0;ch<20;++ch) acc[ch] = (f32x4)(0.f);

  for (int i=s0;i<s1;++i){
    const int q = sortedq[b*NQ+i];
    const float* sp = sig32 + (size_t)(b*NQ+q)*HM*WM;
    for (int i2=tid;i2<10*WM;i2+=256){
      int jr = i2/WM, jc = i2 - jr*WM;
      int gi = clampi(ci0 + jr - 1, 0, HM-1);
      row[jr][jc] = sp[gi*WM + jc];
    }
    __syncthreads();
    #pragma unroll
    for (int ch=0;ch<20;++ch){
      const int idx = ch*256 + tid;      // 0..5119
      const int yo  = idx / WM;          // 0..31
      const int x4  = idx - yo*WM;
      const int y   = y0 + yo;
      const int ci  = y >> 2, r = y & 3;
      const int ciL = ci - ci0 + 1;      // 1..8
      const int ra  = (r<2) ? ciL-1 : ciL;
      const int rb  = ra + 1;
      const bool vedge = (r<2) ? (ci==0) : (ci==HM-1);
      const int cm = max(x4-1,0), cp = min(x4+1,WM-1);
      const float wa = (r==0)?0.375f:(r==1)?0.125f:(r==2)?0.875f:0.625f;
      const float wb = (r==0)?0.625f:(r==1)?0.875f:(r==2)?0.125f:0.375f;
      float am=row[ra][cm], a0=row[ra][x4], ap=row[ra][cp];
      float bm=row[rb][cm], b0=row[rb][x4], bp=row[rb][cp];
      float t0 = vedge ? ((r<2) ? bm : am) : (wa*am + wb*bm);
      float t1 = vedge ? ((r<2) ? b0 : a0) : (wa*a0 + wb*b0);
      float t2 = vedge ? ((r<2) ? bp : ap) : (wa*ap + wb*bp);
      float u0 = (x4==0)    ? t1 : (0.375f*t0 + 0.625f*t1);
      float u1 = (x4==0)    ? t1 : (0.125f*t0 + 0.875f*t1);
      float u2 = (x4==WM-1) ? t1 : (0.875f*t1 + 0.125f*t2);
      float u3 = (x4==WM-1) ? t1 : (0.625f*t1 + 0.375f*t2);
      acc[ch].x = fmaxf(acc[ch].x, u0);
      acc[ch].y = fmaxf(acc[ch].y, u1);
      acc[ch].z = fmaxf(acc[ch].z, u2);
      acc[ch].w = fmaxf(acc[ch].w, u3);
    }
    __syncthreads();
  }

  f32x4* ob = reinterpret_cast<f32x4*>(out) + ((size_t)bc*HO + y0)*(WO/4);
  #pragma unroll
  for (int ch=0;ch<20;++ch)
    __builtin_nontemporal_store(acc[ch], ob + ch*256 + tid);
}

extern "C" void kernel_launch(void* const* d_in, const int* in_sizes, int n_in,
                              void* d_out, int out_size, void* d_ws, size_t ws_size,
                              hipStream_t stream)
{
  const float* logits = (const float*)d_in[0];
  const float* masks  = (const float*)d_in[1];
  float* out = (float*)d_out;

  char* ws = (char*)d_ws;
  size_t off = 0;
  auto alloc = [&](size_t bytes)->void*{
    void* p = ws + off; off = (off + bytes + 255) & ~(size_t)255; return p;
  };
  double*   sig64   = (double*)  alloc((size_t)NB*NQ*HM*WM*sizeof(double));    // 41 MB
  float*    sig32   = (float*)   alloc((size_t)NB*NQ*HM*WM*sizeof(float));     // 20.5 MB
  unsigned long long* ppack = (unsigned long long*)
                               alloc((size_t)NB*G*16*NCELL*sizeof(unsigned long long)); // 52.4 MB
  uint32_t* mids    = (uint32_t*)alloc((size_t)NB*HO*(WO/4)*sizeof(uint32_t));
  double*   scores  = (double*)  alloc(NB*NQ*sizeof(double));
  int*      labels  = (int*)     alloc(NB*NQ*sizeof(int));
  int*      keepf   = (int*)     alloc(NB*NQ*sizeof(int));
  int*      kq      = (int*)     alloc(NB*NQ*sizeof(int));
  int*      Kc      = (int*)     alloc(NB*sizeof(int));
  int*      marea   = (int*)     alloc(NB*NQ*sizeof(int));
  int*      oarea   = (int*)     alloc(NB*NQ*sizeof(int));
  float*    fid     = (float*)   alloc(NB*NQ*sizeof(float));
  int*      chanoff = (int*)     alloc(NB*NCL1*sizeof(int));
  int*      sortedq = (int*)     alloc(NB*NQ*sizeof(int));

  hipLaunchKernelGGL(k_sig_cls, dim3(SIGBLKS+1), dim3(256), 0, stream,
                     masks, sig64, sig32, logits, scores, labels, keepf, kq, Kc,
                     marea, oarea);
  hipLaunchKernelGGL(k_argmax_part, dim3(WM/16, HM/16, NB*G), dim3(256), 0, stream,
                     sig64, scores, kq, Kc, ppack, oarea);
  hipLaunchKernelGGL(k_argmax_comb, dim3(WM/16, HM/16, NB), dim3(256), 0, stream,
                     ppack, mids, marea);
  hipLaunchKernelGGL(k_finalize, dim3(NB), dim3(192), 0, stream,
                     keepf, labels, marea, oarea, fid, chanoff, sortedq);
  hipLaunchKernelGGL(k_sem_pan, dim3(HO/SEMROWS, NB*NCLS+2), dim3(256), 0, stream,
                     sig32, chanoff, sortedq, mids, fid, out);
}